// Round 4
// baseline (289.587 us; speedup 1.0000x reference)
//
#include <hip/hip_runtime.h>
#include <hip/hip_bf16.h>

typedef unsigned short u16;
typedef __attribute__((ext_vector_type(8))) short short8;
typedef __attribute__((ext_vector_type(4))) float f32x4;

__device__ __forceinline__ u16 f2bf(float f){
  unsigned int u = __builtin_bit_cast(unsigned int, f);
  u += 0x7FFFu + ((u >> 16) & 1u);
  return (u16)(u >> 16);
}
__device__ __forceinline__ float bf2f(u16 b){
  unsigned int u = ((unsigned int)b) << 16;
  return __builtin_bit_cast(float, u);
}
__device__ __forceinline__ void gload_lds16(const u16* g, u16* lds){
  __builtin_amdgcn_global_load_lds(
      (const __attribute__((address_space(1))) unsigned int*)g,
      (__attribute__((address_space(3))) unsigned int*)lds, 16, 0, 0);
}

// compiler-level + hw-level fences (rule 18: sched_barrier after asm waitcnt)
#define FENCE_LGKM0() do { asm volatile("s_waitcnt lgkmcnt(0)" ::: "memory"); \
                           __builtin_amdgcn_sched_barrier(0); } while(0)
#define FENCE_VM4()   do { asm volatile("s_waitcnt vmcnt(4)"   ::: "memory"); \
                           __builtin_amdgcn_sched_barrier(0); } while(0)

// ---------------------------------------------------------------------------
// 256x256-tile B^T GEMM, BK=32, 8 waves (2Mx4N), ring-4 LDS K-tile buffers,
// 2 phases/K-tile x 16 MFMA, counted vmcnt(4), T2 chunk-swizzle, T5 setprio.
// C[m,n] = sum_k A[m,k]*B[n,k].
// MODE 0: bf16 store, XCD-swizzled 1-D grid of 384 blocks (projections)
// MODE 1: P = exp(scale*C) causal-masked, bf16 store + rowsum atomics (QK^T)
// MODE 2: C = acc/lsum[row], fp32 store; nt = (bi+1)*8 (PV)
// ---------------------------------------------------------------------------
template<int MODE>
__launch_bounds__(512, 2)
__global__ void gemm256(const u16* __restrict__ A, int lda,
                        const u16* __restrict__ B, int ldb,
                        void* __restrict__ Cout, int ldc,
                        int ntFixed,
                        long long strideAz, long long strideBz, long long strideCz,
                        float* __restrict__ lsum, float scale)
{
  __shared__ __align__(16) u16 As[4*8192];   // 4 ring slots x [256 rows][32 cols]
  __shared__ __align__(16) u16 Bs[4*8192];

  int bi, bj;
  const int bz = blockIdx.z;
  if (MODE == 0){
    const int bid = blockIdx.x;               // 384 blocks; 384/8 = 48 per XCD
    const int swz = (bid & 7)*48 + (bid >> 3);
    bi = swz & 31; bj = swz >> 5;
  } else {
    bi = blockIdx.x; bj = blockIdx.y;
    if (MODE == 1 && bj > bi) return;         // fully-masked upper blocks
  }
  A += (long long)bz * strideAz;
  B += (long long)bz * strideBz;
  const int m0 = bi*256, n0 = bj*256;
  const int nt = (MODE == 2) ? (bi + 1)*8 : ntFixed;

  const int t = threadIdx.x;
  const int lane = t & 63;
  const int w = t >> 6;
  const int wm = w >> 2, wn = w & 3;          // 2 x 4 wave grid
  const int la = lane & 15, lb = lane >> 4;

  // ---- staging geometry: issue i covers tile rows [i*128 + w*16, +16) ----
  // LDS dest is linear (wave-uniform base + lane*16B); source is per-lane
  // pre-swizzled: LDS chunk (R,c) holds global chunk (R, c ^ (R&3)).
  const int sR0 = w*16 + (lane >> 2);
  const int sR1 = 128 + sR0;
  const int scw = ((lane & 3) ^ ((lane >> 2) & 3)) * 8;   // swizzled col (elems)
  const u16* gA0 = A + (long long)(m0 + sR0)*lda + scw;
  const u16* gA1 = A + (long long)(m0 + sR1)*lda + scw;
  const u16* gB0 = B + (long long)(n0 + sR0)*ldb + scw;
  const u16* gB1 = B + (long long)(n0 + sR1)*ldb + scw;
  const int ldsW0 = w*512;                    // elem offset, wave-uniform
  const int ldsW1 = 4096 + w*512;

  // ---- fragment read offsets (swizzled to match staging) -----------------
  const int swz4 = (lb ^ (la & 3)) * 8;
  int rdA[8], rdB[4];
  #pragma unroll
  for (int m = 0; m < 8; ++m) rdA[m] = (wm*128 + m*16 + la)*32 + swz4;
  #pragma unroll
  for (int n = 0; n < 4; ++n) rdB[n] = (wn*64 + n*16 + la)*32 + swz4;

  f32x4 acc[8][4];
  #pragma unroll
  for (int m = 0; m < 8; ++m)
    #pragma unroll
    for (int n = 0; n < 4; ++n) acc[m][n] = (f32x4){0.f,0.f,0.f,0.f};

  // ---- prologue: stage tiles 0 and 1 ------------------------------------
  gload_lds16(gA0,      &As[ldsW0]);        gload_lds16(gA1,      &As[ldsW1]);
  gload_lds16(gB0,      &Bs[ldsW0]);        gload_lds16(gB1,      &Bs[ldsW1]);
  gload_lds16(gA0 + 32, &As[8192 + ldsW0]); gload_lds16(gA1 + 32, &As[8192 + ldsW1]);
  gload_lds16(gB0 + 32, &Bs[8192 + ldsW0]); gload_lds16(gB1 + 32, &Bs[8192 + ldsW1]);
  FENCE_VM4();                               // own tile-0 loads landed
  __builtin_amdgcn_s_barrier();              // -> tile 0 landed for ALL waves

  for (int tt = 0; tt < nt; ++tt){
    const int bb = (tt & 3) * 8192;          // compute buffer
    const int sn = tt + 2;                   // stage target tile
    const int sb = (sn & 3) * 8192;          // != bb, != (tt+1)&3  -> race-free
    short8 af[4], bf[4];

    // ---- phase 1: read A m0-3 + all B; stage A(t+2); MFMA m0-3 ----------
    #pragma unroll
    for (int m = 0; m < 4; ++m) af[m] = *(const short8*)&As[bb + rdA[m]];
    #pragma unroll
    for (int n = 0; n < 4; ++n) bf[n] = *(const short8*)&Bs[bb + rdB[n]];
    if (sn < nt){
      gload_lds16(gA0 + sn*32, &As[sb + ldsW0]);
      gload_lds16(gA1 + sn*32, &As[sb + ldsW1]);
    }
    __builtin_amdgcn_s_barrier();
    FENCE_LGKM0();
    __builtin_amdgcn_s_setprio(1);
    #pragma unroll
    for (int m = 0; m < 4; ++m)
      #pragma unroll
      for (int n = 0; n < 4; ++n)
        acc[m][n] = __builtin_amdgcn_mfma_f32_16x16x32_bf16(af[m], bf[n], acc[m][n], 0,0,0);
    __builtin_amdgcn_s_setprio(0);
    __builtin_amdgcn_s_barrier();

    // ---- phase 2: read A m4-7; stage B(t+2); MFMA m4-7 ------------------
    #pragma unroll
    for (int m = 0; m < 4; ++m) af[m] = *(const short8*)&As[bb + rdA[4+m]];
    if (sn < nt){
      gload_lds16(gB0 + sn*32, &Bs[sb + ldsW0]);
      gload_lds16(gB1 + sn*32, &Bs[sb + ldsW1]);
    }
    __builtin_amdgcn_s_barrier();
    FENCE_LGKM0();
    __builtin_amdgcn_s_setprio(1);
    #pragma unroll
    for (int m = 0; m < 4; ++m)
      #pragma unroll
      for (int n = 0; n < 4; ++n)
        acc[4+m][n] = __builtin_amdgcn_mfma_f32_16x16x32_bf16(af[m], bf[n], acc[4+m][n], 0,0,0);
    __builtin_amdgcn_s_setprio(0);
    FENCE_VM4();                             // tile t+1 fully landed (own loads)
    __builtin_amdgcn_s_barrier();            // ... for all waves
  }

  // ---- epilogues ---------------------------------------------------------
  if (MODE == 0){
    u16* C = (u16*)Cout;
    #pragma unroll
    for (int m = 0; m < 8; ++m)
      #pragma unroll
      for (int r = 0; r < 4; ++r){
        const int row = m0 + wm*128 + m*16 + lb*4 + r;
        #pragma unroll
        for (int n = 0; n < 4; ++n){
          const int col = n0 + wn*64 + n*16 + la;
          C[(long long)row*ldc + col] = f2bf(acc[m][n][r]);
        }
      }
  } else if (MODE == 1){
    u16* C = (u16*)Cout + (long long)bz * strideCz;
    float* lrow = lsum + bz*2048;
    #pragma unroll
    for (int m = 0; m < 8; ++m)
      #pragma unroll
      for (int r = 0; r < 4; ++r){
        const int row = m0 + wm*128 + m*16 + lb*4 + r;     // q index
        float partial = 0.f;
        #pragma unroll
        for (int n = 0; n < 4; ++n){
          const int col = n0 + wn*64 + n*16 + la;          // kv index
          float p = 0.f;
          if (col <= row) p = __expf(acc[m][n][r] * scale); // no-max softmax
          const u16 ub = f2bf(p);
          C[(long long)row*ldc + col] = ub;
          partial += bf2f(ub);                             // sum what PV reads
        }
        #pragma unroll
        for (int off = 1; off < 16; off <<= 1) partial += __shfl_xor(partial, off);
        if (la == 0) atomicAdd(&lrow[row], partial);
      }
  } else {
    float* C = (float*)Cout + (long long)bz * strideCz;
    const float* lrow = lsum + bz*2048;
    #pragma unroll
    for (int m = 0; m < 8; ++m)
      #pragma unroll
      for (int r = 0; r < 4; ++r){
        const int row = m0 + wm*128 + m*16 + lb*4 + r;
        const float inv = 1.f / lrow[row];
        #pragma unroll
        for (int n = 0; n < 4; ++n){
          const int col = n0 + wn*64 + n*16 + la;
          C[(long long)row*ldc + col] = acc[m][n][r] * inv;
        }
      }
  }
}

// fp32 -> bf16 (RNE), 4 elems/thread
__global__ void convert_bf16(const float* __restrict__ src, u16* __restrict__ dst, int n4){
  const int i = blockIdx.x*256 + threadIdx.x;
  if (i >= n4) return;
  const float4 v = ((const float4*)src)[i];
  union { u16 u[4]; unsigned long long ll; } o;
  o.u[0] = f2bf(v.x); o.u[1] = f2bf(v.y); o.u[2] = f2bf(v.z); o.u[3] = f2bf(v.w);
  ((unsigned long long*)dst)[i] = o.ll;
}

// V (cols 2048..3071 of qkv, per batch [2048 x 1024]) -> VT [1024 x 2048]
__global__ void transpose_v(const u16* __restrict__ qkvb, u16* __restrict__ vt){
  __shared__ u16 tile[32][33];
  const int b = blockIdx.z;
  const int s0 = blockIdx.x*32, d0 = blockIdx.y*32;
  const int tx = threadIdx.x, ty = threadIdx.y;
  const u16* src = qkvb + (long long)b*2048*3072 + 2048;
  #pragma unroll
  for (int i = 0; i < 4; i++){
    const int s = ty + i*8;
    tile[s][tx] = src[(long long)(s0 + s)*3072 + d0 + tx];
  }
  __syncthreads();
  u16* dst = vt + (long long)b*1024*2048;
  #pragma unroll
  for (int i = 0; i < 4; i++){
    const int d = ty + i*8;
    dst[(long long)(d0 + d)*2048 + s0 + tx] = tile[tx][d];
  }
}

extern "C" void kernel_launch(void* const* d_in, const int* in_sizes, int n_in,
                              void* d_out, int out_size, void* d_ws, size_t ws_size,
                              hipStream_t stream)
{
  const float* x  = (const float*)d_in[0];
  const float* wq = (const float*)d_in[1];
  const float* wk = (const float*)d_in[2];
  const float* wv = (const float*)d_in[3];

  // workspace layout (bf16 elems unless noted), total ~124 MB
  u16* xb   = (u16*)d_ws;                       // [8192][1024]
  u16* wb   = xb   + (size_t)8192*1024;         // [3072][1024] wq|wk|wv rows
  u16* qkvb = wb   + (size_t)3072*1024;         // [8192][3072] q|k|v cols
  u16* vt   = qkvb + (size_t)8192*3072;         // 4 x [1024][2048]
  u16* Pb   = vt   + (size_t)4*1024*2048;       // 4 x [2048][2048]
  float* lsum = (float*)(Pb + (size_t)4*2048*2048); // 4 x [2048] fp32

  convert_bf16<<<8192, 256, 0, stream>>>(x,  xb, 2097152);
  convert_bf16<<<1024, 256, 0, stream>>>(wq, wb,                     262144);
  convert_bf16<<<1024, 256, 0, stream>>>(wk, wb + (size_t)1024*1024, 262144);
  convert_bf16<<<1024, 256, 0, stream>>>(wv, wb + (size_t)2048*1024, 262144);

  // qkv = xb @ wb^T   [8192 x 3072]
  gemm256<0><<<dim3(384, 1, 1), 512, 0, stream>>>(
      xb, 1024, wb, 1024, (void*)qkvb, 3072, 32, 0, 0, 0, nullptr, 1.f);

  transpose_v<<<dim3(64, 32, 4), dim3(32, 8, 1), 0, stream>>>(qkvb, vt);

  hipMemsetAsync(lsum, 0, (size_t)4*2048*sizeof(float), stream);

  // P = exp(scale * Q K^T) causal-masked, bf16; lsum += rowsums
  gemm256<1><<<dim3(8, 8, 4), 512, 0, stream>>>(
      qkvb, 3072, qkvb + 1024, 3072, (void*)Pb, 2048, 32,
      (long long)2048*3072, (long long)2048*3072, (long long)2048*2048,
      lsum, 0.03125f);

  // O = (P @ VT^T) / lsum  -> fp32 d_out
  gemm256<2><<<dim3(8, 4, 4), 512, 0, stream>>>(
      Pb, 2048, vt, 2048, d_out, 1024, 0,
      (long long)2048*2048, (long long)1024*2048, (long long)2048*1024,
      lsum, 1.f);
}

// Round 7
// 259.907 us; speedup vs baseline: 1.1142x; 1.1142x over previous
//
#include <hip/hip_runtime.h>
#include <hip/hip_bf16.h>

typedef unsigned short u16;
typedef __attribute__((ext_vector_type(8))) short short8;
typedef __attribute__((ext_vector_type(4))) float f32x4;

__device__ __forceinline__ u16 f2bf(float f){
  unsigned int u = __builtin_bit_cast(unsigned int, f);
  u += 0x7FFFu + ((u >> 16) & 1u);
  return (u16)(u >> 16);
}
__device__ __forceinline__ float bf2f(u16 b){
  unsigned int u = ((unsigned int)b) << 16;
  return __builtin_bit_cast(float, u);
}

__device__ __forceinline__ void gload_lds16(const u16* g, u16* lds){
  __builtin_amdgcn_global_load_lds(
      (const __attribute__((address_space(1))) unsigned int*)g,
      (__attribute__((address_space(3))) unsigned int*)lds, 16, 0, 0);
}

// ---------------------------------------------------------------------------
// Templated B^T GEMM: C[m,n] = sum_k A[m,k]*B[n,k], bf16 in, fp32 MFMA accum.
// m97 structure: 128x128 tile, BK=32, 4 waves, global_load_lds dwordx4,
// double-buffered LDS, mfma_f32_16x16x32_bf16. 4 blocks/CU occupancy.
// MODE 0: plain bf16 store (projections)
// MODE 1: P = exp(scale*C) with causal mask, bf16 store + rowsum atomicAdd (QK^T)
// MODE 2: C = acc / lsum[row], fp32 store; K-extent = (bi+1)*128 (PV).
//         1-D grid of 512, complementary-bi pairing: ids d and d+256 decode to
//         bi = p and 15-p so co-resident blocks have uniform combined work.
// ---------------------------------------------------------------------------
template<int MODE>
__launch_bounds__(256, 4)
__global__ void gemm_bt(const u16* __restrict__ A, int lda,
                        const u16* __restrict__ B, int ldb,
                        void* __restrict__ Cout, int ldc,
                        int kIterFixed,
                        long long strideAz, long long strideBz, long long strideCz,
                        float* __restrict__ lsum, float scale)
{
  __shared__ __align__(16) u16 As[2][128*32];
  __shared__ __align__(16) u16 Bs[2][128*32];
  int bi, bj, bz;
  if (MODE == 2){
    const int d = blockIdx.x;        // 512 blocks; d and d+256 share a CU (rr)
    const int r = d & 255;
    bi = (d >> 8) ? (15 - (r & 7)) : (r & 7);   // complementary pairing
    bj = (r >> 3) & 7;
    bz = r >> 6;
  } else {
    bi = blockIdx.x; bj = blockIdx.y; bz = blockIdx.z;
    if (MODE == 1 && bj > bi) return;  // upper-triangular blocks: fully masked
  }
  A += (long long)bz * strideAz;
  B += (long long)bz * strideBz;
  const int m0 = bi*128, n0 = bj*128;
  const int kIters = (MODE == 2) ? (bi + 1) * 4 : kIterFixed;
  const int t = threadIdx.x;
  const int lane = t & 63;
  const int w = t >> 6;
  const int wm = w >> 1, wn = w & 1;
  const int la = lane & 15, lb = lane >> 4;

  // staging: 512 chunks of 8 bf16 (16B) per 128x32 tile; thread t takes chunks t, t+256
  const int r0 = t >> 2,          q0c = (t & 3) << 3;
  const int r1 = (t + 256) >> 2,  q1c = (t & 3) << 3;
  const int ldsb0 = (t & ~63) << 3;          // wave-uniform LDS elem base, issue 0
  const int ldsb1 = (256 + (t & ~63)) << 3;  // issue 1

  f32x4 acc[4][4];
  #pragma unroll
  for (int i = 0; i < 4; i++)
    #pragma unroll
    for (int j = 0; j < 4; j++) acc[i][j] = (f32x4){0.f, 0.f, 0.f, 0.f};

  // prologue: stage k-tile 0 into buffer 0
  gload_lds16(A + (long long)(m0 + r0)*lda + q0c, &As[0][ldsb0]);
  gload_lds16(A + (long long)(m0 + r1)*lda + q1c, &As[0][ldsb1]);
  gload_lds16(B + (long long)(n0 + r0)*ldb + q0c, &Bs[0][ldsb0]);
  gload_lds16(B + (long long)(n0 + r1)*ldb + q1c, &Bs[0][ldsb1]);
  asm volatile("s_waitcnt vmcnt(0)" ::: "memory");
  __syncthreads();

  for (int kt = 0; kt < kIters; ++kt){
    const int cur = kt & 1;
    if (kt + 1 < kIters){
      const int k0 = (kt + 1) * 32;
      gload_lds16(A + (long long)(m0 + r0)*lda + k0 + q0c, &As[cur^1][ldsb0]);
      gload_lds16(A + (long long)(m0 + r1)*lda + k0 + q1c, &As[cur^1][ldsb1]);
      gload_lds16(B + (long long)(n0 + r0)*ldb + k0 + q0c, &Bs[cur^1][ldsb0]);
      gload_lds16(B + (long long)(n0 + r1)*ldb + k0 + q1c, &Bs[cur^1][ldsb1]);
    }
    short8 af[4], bfr[4];
    #pragma unroll
    for (int mi = 0; mi < 4; mi++)
      af[mi] = *(const short8*)&As[cur][(wm*64 + mi*16 + la)*32 + lb*8];
    #pragma unroll
    for (int ni = 0; ni < 4; ni++)
      bfr[ni] = *(const short8*)&Bs[cur][(wn*64 + ni*16 + la)*32 + lb*8];
    #pragma unroll
    for (int mi = 0; mi < 4; mi++)
      #pragma unroll
      for (int ni = 0; ni < 4; ni++)
        acc[mi][ni] = __builtin_amdgcn_mfma_f32_16x16x32_bf16(af[mi], bfr[ni], acc[mi][ni], 0, 0, 0);
    asm volatile("s_waitcnt vmcnt(0)" ::: "memory");
    __syncthreads();
  }

  if (MODE == 0){
    u16* C = (u16*)Cout;
    #pragma unroll
    for (int mi = 0; mi < 4; mi++)
      #pragma unroll
      for (int r = 0; r < 4; r++){
        const int row = m0 + wm*64 + mi*16 + lb*4 + r;
        #pragma unroll
        for (int ni = 0; ni < 4; ni++){
          const int col = n0 + wn*64 + ni*16 + la;
          C[(long long)row*ldc + col] = f2bf(acc[mi][ni][r]);
        }
      }
  } else if (MODE == 1){
    u16* C = (u16*)Cout + (long long)bz * strideCz;
    float* lrow = lsum + bz*2048;
    #pragma unroll
    for (int mi = 0; mi < 4; mi++)
      #pragma unroll
      for (int r = 0; r < 4; r++){
        const int row = m0 + wm*64 + mi*16 + lb*4 + r;   // q index
        float partial = 0.f;
        #pragma unroll
        for (int ni = 0; ni < 4; ni++){
          const int col = n0 + wn*64 + ni*16 + la;       // kv index
          float p = 0.f;
          if (col <= row) p = __expf(acc[mi][ni][r] * scale);  // no-max softmax: |s|<~2
          const u16 ub = f2bf(p);
          C[(long long)row*ldc + col] = ub;
          partial += bf2f(ub);                           // sum exactly what PV will read
        }
        #pragma unroll
        for (int off = 1; off < 16; off <<= 1) partial += __shfl_xor(partial, off);
        if (la == 0) atomicAdd(&lrow[row], partial);
      }
  } else {
    float* C = (float*)Cout + (long long)bz * strideCz;
    const float* lrow = lsum + bz*2048;
    #pragma unroll
    for (int mi = 0; mi < 4; mi++)
      #pragma unroll
      for (int r = 0; r < 4; r++){
        const int row = m0 + wm*64 + mi*16 + lb*4 + r;
        const float inv = 1.f / lrow[row];
        #pragma unroll
        for (int ni = 0; ni < 4; ni++){
          const int col = n0 + wn*64 + ni*16 + la;
          C[(long long)row*ldc + col] = acc[mi][ni][r] * inv;
        }
      }
  }
}

// fp32 -> bf16 (RNE), 4 elems/thread
__global__ void convert_bf16(const float* __restrict__ src, u16* __restrict__ dst, int n4){
  const int i = blockIdx.x*256 + threadIdx.x;
  if (i >= n4) return;
  const float4 v = ((const float4*)src)[i];
  union { u16 u[4]; unsigned long long ll; } o;
  o.u[0] = f2bf(v.x); o.u[1] = f2bf(v.y); o.u[2] = f2bf(v.z); o.u[3] = f2bf(v.w);
  ((unsigned long long*)dst)[i] = o.ll;
}

// V (cols 2048..3071 of qkv, per batch [2048 x 1024]) -> VT [1024 x 2048]
__global__ void transpose_v(const u16* __restrict__ qkvb, u16* __restrict__ vt){
  __shared__ u16 tile[32][33];
  const int b = blockIdx.z;
  const int s0 = blockIdx.x*32, d0 = blockIdx.y*32;
  const int tx = threadIdx.x, ty = threadIdx.y;
  const u16* src = qkvb + (long long)b*2048*3072 + 2048;
  #pragma unroll
  for (int i = 0; i < 4; i++){
    const int s = ty + i*8;
    tile[s][tx] = src[(long long)(s0 + s)*3072 + d0 + tx];
  }
  __syncthreads();
  u16* dst = vt + (long long)b*1024*2048;
  #pragma unroll
  for (int i = 0; i < 4; i++){
    const int d = ty + i*8;
    dst[(long long)(d0 + d)*2048 + s0 + tx] = tile[tx][d];
  }
}

extern "C" void kernel_launch(void* const* d_in, const int* in_sizes, int n_in,
                              void* d_out, int out_size, void* d_ws, size_t ws_size,
                              hipStream_t stream)
{
  const float* x  = (const float*)d_in[0];
  const float* wq = (const float*)d_in[1];
  const float* wk = (const float*)d_in[2];
  const float* wv = (const float*)d_in[3];

  // workspace layout (bf16 elems unless noted), total ~124 MB
  u16* xb   = (u16*)d_ws;                       // [8192][1024]
  u16* wb   = xb   + (size_t)8192*1024;         // [3072][1024] wq|wk|wv rows
  u16* qkvb = wb   + (size_t)3072*1024;         // [8192][3072] q|k|v cols
  u16* vt   = qkvb + (size_t)8192*3072;         // 4 x [1024][2048]
  u16* Pb   = vt   + (size_t)4*1024*2048;       // 4 x [2048][2048]
  float* lsum = (float*)(Pb + (size_t)4*2048*2048); // 4 x [2048] fp32

  convert_bf16<<<8192, 256, 0, stream>>>(x,  xb, 2097152);
  convert_bf16<<<1024, 256, 0, stream>>>(wq, wb,                     262144);
  convert_bf16<<<1024, 256, 0, stream>>>(wk, wb + (size_t)1024*1024, 262144);
  convert_bf16<<<1024, 256, 0, stream>>>(wv, wb + (size_t)2048*1024, 262144);

  // qkv = xb @ wb^T   [8192 x 3072]
  gemm_bt<0><<<dim3(64, 24, 1), 256, 0, stream>>>(
      xb, 1024, wb, 1024, (void*)qkvb, 3072, 32, 0, 0, 0, nullptr, 1.f);

  transpose_v<<<dim3(64, 32, 4), dim3(32, 8, 1), 0, stream>>>(qkvb, vt);

  hipMemsetAsync(lsum, 0, (size_t)4*2048*sizeof(float), stream);

  // P = exp(scale * Q K^T) causal-masked, bf16; lsum += rowsums
  gemm_bt<1><<<dim3(16, 16, 4), 256, 0, stream>>>(
      qkvb, 3072, qkvb + 1024, 3072, (void*)Pb, 2048, 32,
      (long long)2048*3072, (long long)2048*3072, (long long)2048*2048,
      lsum, 0.03125f);

  // O = (P @ VT^T) / lsum  -> fp32 d_out, paired-bi 1-D grid
  gemm_bt<2><<<dim3(512, 1, 1), 256, 0, stream>>>(
      Pb, 2048, vt, 2048, d_out, 1024, 0,
      (long long)2048*2048, (long long)1024*2048, (long long)2048*1024,
      lsum, 1.f);
}

// Round 10
// 259.851 us; speedup vs baseline: 1.1144x; 1.0002x over previous
//
#include <hip/hip_runtime.h>
#include <hip/hip_bf16.h>

typedef unsigned short u16;
typedef __attribute__((ext_vector_type(8))) short short8;
typedef __attribute__((ext_vector_type(4))) float f32x4;

__device__ __forceinline__ u16 f2bf(float f){
  unsigned int u = __builtin_bit_cast(unsigned int, f);
  u += 0x7FFFu + ((u >> 16) & 1u);
  return (u16)(u >> 16);
}
__device__ __forceinline__ float bf2f(u16 b){
  unsigned int u = ((unsigned int)b) << 16;
  return __builtin_bit_cast(float, u);
}
__device__ __forceinline__ void gload_lds16(const u16* g, u16* lds){
  __builtin_amdgcn_global_load_lds(
      (const __attribute__((address_space(1))) unsigned int*)g,
      (__attribute__((address_space(3))) unsigned int*)lds, 16, 0, 0);
}

#define FENCE_LGKM0() do { asm volatile("s_waitcnt lgkmcnt(0)" ::: "memory"); \
                           __builtin_amdgcn_sched_barrier(0); } while(0)
#define FENCE_VMN(N)  do { asm volatile("s_waitcnt vmcnt(" #N ")" ::: "memory"); \
                           __builtin_amdgcn_sched_barrier(0); } while(0)

// half-tile stage: 2 x global_load_lds per thread (1024 chunks of 16B total)
__device__ __forceinline__ void stage_half(const u16* p, u16* arr, int bufhalf, int dstOff){
  u16* d = arr + bufhalf*8192 + dstOff;
  gload_lds16(p, d);          // kk=0 block
  gload_lds16(p + 32, d + 4096); // kk=1 block
}

// ---------------------------------------------------------------------------
// m201-faithful 8-phase 256x256 B^T GEMM, BK=64, 8 waves (2Mx4N), NS=16 (K=1024).
// LDS per matrix: [2 buf][2 half][2 kk][128 row][32 col] bf16, st_16x32 swizzle
// (col ^= 16 when row&8, applied via pre-swizzled global src + swizzled ds_read).
// Schedule per K-step s (buf=s&1): 4 phases q:
//   q0: dsA(m0,1)+dsB(all8); stage A0(s+1)->buf^1 | q1: dsA(m2,3); stage A1(s+1)->buf^1
//   q2: dsA(m4,5); stage B0(s+2)->buf          | q3: dsA(m6,7); stage B1(s+2)->buf
//   each: barrier; lgkmcnt(0); setprio(1); 16 MFMA; setprio(0); [q3: vmcnt(4)]; barrier
// Ledger: at boundary s->s+1, vmcnt(4) leaves exactly B(s+2)'s 4 loads in flight;
// A(s+1),B(s+1) retired. B(s+2) overwrites Bs[buf] only after its q0 consumption.
// MODE 0: bf16 store, XCD-swizzled 384-block grid.  MODE 1: exp+mask+rowsum.
// ---------------------------------------------------------------------------
template<int MODE>
__launch_bounds__(512, 2)
__global__ void gemm8p(const u16* __restrict__ A, int lda,
                       const u16* __restrict__ B, int ldb,
                       void* __restrict__ Cout, int ldc,
                       long long strideAz, long long strideBz, long long strideCz,
                       float* __restrict__ lsum, float scale)
{
  __shared__ __align__(16) u16 As[32768];   // 64 KB
  __shared__ __align__(16) u16 Bs[32768];   // 64 KB
  constexpr int NS = 16;                    // K = 1024

  int bi, bj, bz;
  if (MODE == 0){
    const int bid = blockIdx.x;             // 384 = 8 XCD x 48
    const int swz = (bid & 7)*48 + (bid >> 3);
    bi = swz & 31; bj = swz >> 5; bz = 0;
  } else {
    bi = blockIdx.x; bj = blockIdx.y; bz = blockIdx.z;
    if (bj > bi) return;                    // causal: fully-masked 256-blocks
  }
  A += (long long)bz * strideAz;
  B += (long long)bz * strideBz;
  const int m0 = bi*256, n0 = bj*256;

  const int t = threadIdx.x;
  const int lane = t & 63;
  const int w = t >> 6;
  const int wm = w >> 2, wn = w & 3;        // 2M x 4N wave grid
  const int la = lane & 15, lb = lane >> 4;

  // ---- staging source (pre-swizzled): chunk t covers (row=t>>2, colchunk=(t&3)^((t>>5&1)<<1))
  const int srow = (t >> 2) & 127;
  const int scol = ((t & 3) ^ (((t >> 5) & 1) << 1)) * 8;
  const u16* pA0 = A + (long long)(m0 +       srow)*lda + scol;
  const u16* pA1 = A + (long long)(m0 + 128 + srow)*lda + scol;
  const u16* pB0 = B + (long long)(n0 +       srow)*ldb + scol;
  const u16* pB1 = B + (long long)(n0 + 128 + srow)*ldb + scol;
  const int dstOff = (t & ~63) * 8;         // wave-uniform LDS elem base

  // ---- ds_read col swizzle: col = lb*8 ^ (row&8)<<1, row bit3 == la bit3
  const int colr = (lb*8) ^ ((la & 8) << 1);

  f32x4 acc[8][4];
  #pragma unroll
  for (int m = 0; m < 8; ++m)
    #pragma unroll
    for (int n = 0; n < 4; ++n) acc[m][n] = (f32x4){0.f,0.f,0.f,0.f};

  // ---- prologue: B(0),A(0) then B(1); vmcnt(4) -> step-0 halves landed ----
  stage_half(pB0,      Bs, 0, dstOff);
  stage_half(pB1,      Bs, 1, dstOff);
  stage_half(pA0,      As, 0, dstOff);
  stage_half(pA1,      As, 1, dstOff);
  stage_half(pB0 + 64, Bs, 2, dstOff);      // buf1 half0
  stage_half(pB1 + 64, Bs, 3, dstOff);      // buf1 half1
  FENCE_VMN(4);
  __builtin_amdgcn_s_barrier();

  for (int s = 0; s < NS; ++s){
    const int buf = s & 1;
    const int Ab = (buf*2 + wm) * 8192;
    const int Bb = (buf*2 + (wn >> 1)) * 8192;
    short8 bfr[4][2];
    #pragma unroll
    for (int q = 0; q < 4; ++q){
      short8 af[2][2];
      #pragma unroll
      for (int mm = 0; mm < 2; ++mm)
        #pragma unroll
        for (int kk = 0; kk < 2; ++kk)
          af[mm][kk] = *(const short8*)&As[Ab + kk*4096 + ((2*q+mm)*16 + la)*32 + colr];
      if (q == 0){
        #pragma unroll
        for (int n = 0; n < 4; ++n)
          #pragma unroll
          for (int kk = 0; kk < 2; ++kk)
            bfr[n][kk] = *(const short8*)&Bs[Bb + kk*4096 + ((wn&1)*64 + n*16 + la)*32 + colr];
      }
      // one half-tile stage per phase (see ledger in header comment)
      if (q == 0 && s+1 < NS) stage_half(pA0 + (s+1)*64, As, ((s+1)&1)*2 + 0, dstOff);
      if (q == 1 && s+1 < NS) stage_half(pA1 + (s+1)*64, As, ((s+1)&1)*2 + 1, dstOff);
      if (q == 2 && s+2 < NS) stage_half(pB0 + (s+2)*64, Bs, buf*2 + 0, dstOff);
      if (q == 3 && s+2 < NS) stage_half(pB1 + (s+2)*64, Bs, buf*2 + 1, dstOff);

      __builtin_amdgcn_s_barrier();
      FENCE_LGKM0();
      __builtin_amdgcn_s_setprio(1);
      #pragma unroll
      for (int mm = 0; mm < 2; ++mm)
        #pragma unroll
        for (int n = 0; n < 4; ++n)
          #pragma unroll
          for (int kk = 0; kk < 2; ++kk)
            acc[2*q+mm][n] = __builtin_amdgcn_mfma_f32_16x16x32_bf16(
                                af[mm][kk], bfr[n][kk], acc[2*q+mm][n], 0,0,0);
      __builtin_amdgcn_s_setprio(0);
      if (q == 3 && s+1 < NS){
        if (s+2 < NS) { FENCE_VMN(4); } else { FENCE_VMN(0); }
      }
      __builtin_amdgcn_s_barrier();
    }
  }

  // ---- epilogues ---------------------------------------------------------
  if (MODE == 0){
    u16* C = (u16*)Cout;
    #pragma unroll
    for (int m = 0; m < 8; ++m)
      #pragma unroll
      for (int r = 0; r < 4; ++r){
        const int row = m0 + wm*128 + m*16 + lb*4 + r;
        #pragma unroll
        for (int n = 0; n < 4; ++n){
          const int col = n0 + wn*64 + n*16 + la;
          C[(long long)row*ldc + col] = f2bf(acc[m][n][r]);
        }
      }
  } else {
    u16* C = (u16*)Cout + (long long)bz * strideCz;
    float* lrow = lsum + bz*2048;
    #pragma unroll
    for (int m = 0; m < 8; ++m)
      #pragma unroll
      for (int r = 0; r < 4; ++r){
        const int row = m0 + wm*128 + m*16 + lb*4 + r;     // q index
        float partial = 0.f;
        #pragma unroll
        for (int n = 0; n < 4; ++n){
          const int col = n0 + wn*64 + n*16 + la;          // kv index
          float p = 0.f;
          if (col <= row) p = __expf(acc[m][n][r] * scale); // no-max softmax
          const u16 ub = f2bf(p);
          C[(long long)row*ldc + col] = ub;
          partial += bf2f(ub);                             // sum what PV reads
        }
        #pragma unroll
        for (int off = 1; off < 16; off <<= 1) partial += __shfl_xor(partial, off);
        if (la == 0) atomicAdd(&lrow[row], partial);
      }
  }
}

// ---------------------------------------------------------------------------
// r7-proven 128x128 m97-structure kernel, used for PV (MODE 2 only).
// ---------------------------------------------------------------------------
template<int MODE>
__launch_bounds__(256, 4)
__global__ void gemm_bt(const u16* __restrict__ A, int lda,
                        const u16* __restrict__ B, int ldb,
                        void* __restrict__ Cout, int ldc,
                        int kIterFixed,
                        long long strideAz, long long strideBz, long long strideCz,
                        float* __restrict__ lsum, float scale)
{
  __shared__ __align__(16) u16 As[2][128*32];
  __shared__ __align__(16) u16 Bs[2][128*32];
  int bi, bj, bz;
  if (MODE == 2){
    const int d = blockIdx.x;        // 512 blocks; d and d+256 share a CU (rr)
    const int r = d & 255;
    bi = (d >> 8) ? (15 - (r & 7)) : (r & 7);   // complementary pairing
    bj = (r >> 3) & 7;
    bz = r >> 6;
  } else {
    bi = blockIdx.x; bj = blockIdx.y; bz = blockIdx.z;
  }
  A += (long long)bz * strideAz;
  B += (long long)bz * strideBz;
  const int m0 = bi*128, n0 = bj*128;
  const int kIters = (MODE == 2) ? (bi + 1) * 4 : kIterFixed;
  const int t = threadIdx.x;
  const int lane = t & 63;
  const int w = t >> 6;
  const int wm = w >> 1, wn = w & 1;
  const int la = lane & 15, lb = lane >> 4;

  const int r0 = t >> 2,          q0c = (t & 3) << 3;
  const int r1 = (t + 256) >> 2,  q1c = (t & 3) << 3;
  const int ldsb0 = (t & ~63) << 3;
  const int ldsb1 = (256 + (t & ~63)) << 3;

  f32x4 acc[4][4];
  #pragma unroll
  for (int i = 0; i < 4; i++)
    #pragma unroll
    for (int j = 0; j < 4; j++) acc[i][j] = (f32x4){0.f, 0.f, 0.f, 0.f};

  gload_lds16(A + (long long)(m0 + r0)*lda + q0c, &As[0][ldsb0]);
  gload_lds16(A + (long long)(m0 + r1)*lda + q1c, &As[0][ldsb1]);
  gload_lds16(B + (long long)(n0 + r0)*ldb + q0c, &Bs[0][ldsb0]);
  gload_lds16(B + (long long)(n0 + r1)*ldb + q1c, &Bs[0][ldsb1]);
  asm volatile("s_waitcnt vmcnt(0)" ::: "memory");
  __syncthreads();

  for (int kt = 0; kt < kIters; ++kt){
    const int cur = kt & 1;
    if (kt + 1 < kIters){
      const int k0 = (kt + 1) * 32;
      gload_lds16(A + (long long)(m0 + r0)*lda + k0 + q0c, &As[cur^1][ldsb0]);
      gload_lds16(A + (long long)(m0 + r1)*lda + k0 + q1c, &As[cur^1][ldsb1]);
      gload_lds16(B + (long long)(n0 + r0)*ldb + k0 + q0c, &Bs[cur^1][ldsb0]);
      gload_lds16(B + (long long)(n0 + r1)*ldb + k0 + q1c, &Bs[cur^1][ldsb1]);
    }
    short8 af[4], bfr[4];
    #pragma unroll
    for (int mi = 0; mi < 4; mi++)
      af[mi] = *(const short8*)&As[cur][(wm*64 + mi*16 + la)*32 + lb*8];
    #pragma unroll
    for (int ni = 0; ni < 4; ni++)
      bfr[ni] = *(const short8*)&Bs[cur][(wn*64 + ni*16 + la)*32 + lb*8];
    #pragma unroll
    for (int mi = 0; mi < 4; mi++)
      #pragma unroll
      for (int ni = 0; ni < 4; ni++)
        acc[mi][ni] = __builtin_amdgcn_mfma_f32_16x16x32_bf16(af[mi], bfr[ni], acc[mi][ni], 0, 0, 0);
    asm volatile("s_waitcnt vmcnt(0)" ::: "memory");
    __syncthreads();
  }

  {
    float* C = (float*)Cout + (long long)bz * strideCz;
    const float* lrow = lsum + bz*2048;
    #pragma unroll
    for (int mi = 0; mi < 4; mi++)
      #pragma unroll
      for (int r = 0; r < 4; r++){
        const int row = m0 + wm*64 + mi*16 + lb*4 + r;
        const float inv = 1.f / lrow[row];
        #pragma unroll
        for (int ni = 0; ni < 4; ni++){
          const int col = n0 + wn*64 + ni*16 + la;
          C[(long long)row*ldc + col] = acc[mi][ni][r] * inv;
        }
      }
  }
}

// fp32 -> bf16 (RNE), 4 elems/thread
__global__ void convert_bf16(const float* __restrict__ src, u16* __restrict__ dst, int n4){
  const int i = blockIdx.x*256 + threadIdx.x;
  if (i >= n4) return;
  const float4 v = ((const float4*)src)[i];
  union { u16 u[4]; unsigned long long ll; } o;
  o.u[0] = f2bf(v.x); o.u[1] = f2bf(v.y); o.u[2] = f2bf(v.z); o.u[3] = f2bf(v.w);
  ((unsigned long long*)dst)[i] = o.ll;
}

// V (cols 2048..3071 of qkv, per batch [2048 x 1024]) -> VT [1024 x 2048]
__global__ void transpose_v(const u16* __restrict__ qkvb, u16* __restrict__ vt){
  __shared__ u16 tile[32][33];
  const int b = blockIdx.z;
  const int s0 = blockIdx.x*32, d0 = blockIdx.y*32;
  const int tx = threadIdx.x, ty = threadIdx.y;
  const u16* src = qkvb + (long long)b*2048*3072 + 2048;
  #pragma unroll
  for (int i = 0; i < 4; i++){
    const int s = ty + i*8;
    tile[s][tx] = src[(long long)(s0 + s)*3072 + d0 + tx];
  }
  __syncthreads();
  u16* dst = vt + (long long)b*1024*2048;
  #pragma unroll
  for (int i = 0; i < 4; i++){
    const int d = ty + i*8;
    dst[(long long)(d0 + d)*2048 + s0 + tx] = tile[tx][d];
  }
}

extern "C" void kernel_launch(void* const* d_in, const int* in_sizes, int n_in,
                              void* d_out, int out_size, void* d_ws, size_t ws_size,
                              hipStream_t stream)
{
  const float* x  = (const float*)d_in[0];
  const float* wq = (const float*)d_in[1];
  const float* wk = (const float*)d_in[2];
  const float* wv = (const float*)d_in[3];

  u16* xb   = (u16*)d_ws;                       // [8192][1024]
  u16* wb   = xb   + (size_t)8192*1024;         // [3072][1024]
  u16* qkvb = wb   + (size_t)3072*1024;         // [8192][3072]
  u16* vt   = qkvb + (size_t)8192*3072;         // 4 x [1024][2048]
  u16* Pb   = vt   + (size_t)4*1024*2048;       // 4 x [2048][2048]
  float* lsum = (float*)(Pb + (size_t)4*2048*2048); // 4 x [2048] fp32

  convert_bf16<<<8192, 256, 0, stream>>>(x,  xb, 2097152);
  convert_bf16<<<1024, 256, 0, stream>>>(wq, wb,                     262144);
  convert_bf16<<<1024, 256, 0, stream>>>(wk, wb + (size_t)1024*1024, 262144);
  convert_bf16<<<1024, 256, 0, stream>>>(wv, wb + (size_t)2048*1024, 262144);

  // qkv = xb @ wb^T   [8192 x 3072], 8-phase 256^2 kernel
  gemm8p<0><<<dim3(384, 1, 1), 512, 0, stream>>>(
      xb, 1024, wb, 1024, (void*)qkvb, 3072, 0, 0, 0, nullptr, 1.f);

  transpose_v<<<dim3(64, 32, 4), dim3(32, 8, 1), 0, stream>>>(qkvb, vt);

  hipMemsetAsync(lsum, 0, (size_t)4*2048*sizeof(float), stream);

  // P = exp(scale * Q K^T) causal-masked, bf16; lsum += rowsums (8-phase)
  gemm8p<1><<<dim3(8, 8, 4), 512, 0, stream>>>(
      qkvb, 3072, qkvb + 1024, 3072, (void*)Pb, 2048,
      (long long)2048*3072, (long long)2048*3072, (long long)2048*2048,
      lsum, 0.03125f);

  // O = (P @ VT^T) / lsum  -> fp32 d_out, paired-bi 1-D grid (r7 kernel)
  gemm_bt<2><<<dim3(512, 1, 1), 256, 0, stream>>>(
      Pb, 2048, vt, 2048, d_out, 1024, 0,
      (long long)2048*2048, (long long)1024*2048, (long long)2048*1024,
      lsum, 1.f);
}